// Round 4
// baseline (108.303 us; speedup 1.0000x reference)
//
#include <hip/hip_runtime.h>

// RelativePositionalEncoding2D: out[b,i,j,e] = W[e, pos] + bias[e]
//   pos = clip(idxs[b,j] - idxs[b,i], -32, 32) + 32
// Shapes: B=1, S=1024, E=128, N=65. Output fp32 (1,S,S,E) = 512 MiB -> pure
// HBM-write-bound (floor ~78us at 6.8 TB/s measured fill BW).
//
// R3 -> R4: single-generation persistent mapping. 1024 blocks (one full
// i-row each, 512 KiB of stores) x 37.4 KB LDS = exactly 4 blocks/CU, one
// generation: prologue (table fill) runs once per resident slot instead of
// twice, no drain/refill bubble at a generation boundary, uniform tail.
// Unroll 8 keeps 8 independent ds_read_b128 -> global_store(nt) in flight.

#define MAXGAP 32
#define NIDX   65     // 2*MAXGAP+1
#define EDIM   128
#define E4     32     // EDIM/4 float4 per output row

typedef float f32x4 __attribute__((ext_vector_type(4)));

__global__ __launch_bounds__(256) void relpos2d_kernel(
    const int* __restrict__ idxs,
    const float* __restrict__ W,       // (E, N) row-major
    const float* __restrict__ bias,    // (E,)
    f32x4* __restrict__ out,           // (S*S, E4)
    int S)
{
    __shared__ float table[NIDX][EDIM];   // 33,280 B
    __shared__ int   jidx[1024];          // full idxs row (S <= 1024)

    // table[p][e] = W[e*N + p] + bias[e]
    for (int t = threadIdx.x; t < NIDX * EDIM; t += 256) {
        int p = t >> 7;
        int e = t & 127;
        table[p][e] = W[e * NIDX + p] + bias[e];
    }

    const int i = blockIdx.x;            // one block per output row-block i

    // stage idxs[j] for the whole row
    for (int t = threadIdx.x; t < S; t += 256)
        jidx[t] = idxs[t];

    __syncthreads();

    const int lane4 = threadIdx.x & 31;   // float4 slot within the 512B row
    const int jsub  = threadIdx.x >> 5;   // 0..7: j within this step
    const int idx_i = idxs[i];            // scalar (block-uniform)

    f32x4* __restrict__ orow = out + (size_t)i * S * E4;

    #pragma unroll 8
    for (int jj = 0; jj < S; jj += 8) {
        int j = jj + jsub;
        int d = jidx[j] - idx_i;                       // LDS broadcast read
        d = d < -MAXGAP ? -MAXGAP : (d > MAXGAP ? MAXGAP : d);
        int p = d + MAXGAP;

        f32x4 v = reinterpret_cast<const f32x4*>(&table[p][0])[lane4];
        __builtin_nontemporal_store(v, &orow[(size_t)j * E4 + lane4]);
    }
}

extern "C" void kernel_launch(void* const* d_in, const int* in_sizes, int n_in,
                              void* d_out, int out_size, void* d_ws, size_t ws_size,
                              hipStream_t stream) {
    const int*   idxs = (const int*)  d_in[0];   // (B*S,) int32, B=1
    const float* W    = (const float*)d_in[1];   // (E, N) fp32
    const float* bias = (const float*)d_in[2];   // (E,)  fp32

    f32x4* out = (f32x4*)d_out;

    const int S    = in_sizes[0];   // B=1
    const int grid = S;             // 1024 blocks: one i-row each, 4/CU, 1 gen

    relpos2d_kernel<<<grid, 256, 0, stream>>>(idxs, W, bias, out, S);
}

// Round 5
// 101.054 us; speedup vs baseline: 1.0717x; 1.0717x over previous
//
#include <hip/hip_runtime.h>

// RelativePositionalEncoding2D: out[b,i,j,e] = W[e, pos] + bias[e]
//   pos = clip(idxs[b,j] - idxs[b,i], -32, 32) + 32
// Shapes: B=1, S=1024, E=128, N=65. Output fp32 (1,S,S,E) = 512 MiB -> pure
// HBM-write-bound (floor ~80us at ~6.7 TB/s measured fill BW).
//
// R4 -> R5: fix the UNCOALESCED table-fill prologue. Old fill read W with
// lanes 260B apart (64 cachelines/wave-load, ~0.5GB of L2 transactions per
// resident generation ~= 15us of dead time before any store). New fill:
// thread t loads W[t] (fully coalesced), scatters into LDS instead. LDS row
// stride padded to 132 floats (528B: 16B-aligned for ds_read_b128; write
// conflict is 8-way on a one-time loop = negligible).
// Everything else = R3 best-known: 2048 half-row blocks, nt stores, unroll 4.

#define MAXGAP 32
#define NIDX   65     // 2*MAXGAP+1
#define EDIM   128
#define E4     32     // EDIM/4 float4 per output row
#define PADE   132    // padded row stride in floats (528B, 16B-aligned)
#define CHUNKS 2      // half-rows per i

typedef float f32x4 __attribute__((ext_vector_type(4)));

__global__ __launch_bounds__(256) void relpos2d_kernel(
    const int* __restrict__ idxs,
    const float* __restrict__ W,       // (E, N) row-major
    const float* __restrict__ bias,    // (E,)
    f32x4* __restrict__ out,           // (S*S, E4)
    int S, int halfS)
{
    __shared__ float table[NIDX * PADE];  // 65*132*4 = 34,320 B
    __shared__ int   jidx[512];           // halfS entries

    // table[p][e] = W[e*N + p] + bias[e]; read W coalesced, scatter to LDS.
    for (int t = threadIdx.x; t < NIDX * EDIM; t += 256) {
        float w = W[t];              // coalesced: t = e*NIDX + p
        int e = t / NIDX;            // magic-mul (constant divisor)
        int p = t - e * NIDX;
        table[p * PADE + e] = w + bias[e];
    }

    const int i     = blockIdx.x >> 1;       // CHUNKS == 2
    const int chunk = blockIdx.x & (CHUNKS - 1);
    const int jbase = chunk * halfS;

    // stage this block's idxs[j] slice
    for (int t = threadIdx.x; t < halfS; t += 256)
        jidx[t] = idxs[jbase + t];

    __syncthreads();

    const int lane4 = threadIdx.x & 31;   // float4 slot within the 512B row
    const int jsub  = threadIdx.x >> 5;   // 0..7: j within this step
    const int idx_i = idxs[i];

    f32x4* __restrict__ orow = out + (size_t)i * S * E4 + (size_t)jbase * E4;

    #pragma unroll 4
    for (int jj = 0; jj < halfS; jj += 8) {
        int j = jj + jsub;
        int d = jidx[j] - idx_i;                       // LDS broadcast read
        d = d < -MAXGAP ? -MAXGAP : (d > MAXGAP ? MAXGAP : d);
        int p = d + MAXGAP;

        f32x4 v = reinterpret_cast<const f32x4*>(&table[p * PADE])[lane4];
        __builtin_nontemporal_store(v, &orow[(size_t)j * E4 + lane4]);
    }
}

extern "C" void kernel_launch(void* const* d_in, const int* in_sizes, int n_in,
                              void* d_out, int out_size, void* d_ws, size_t ws_size,
                              hipStream_t stream) {
    const int*   idxs = (const int*)  d_in[0];   // (B*S,) int32, B=1
    const float* W    = (const float*)d_in[1];   // (E, N) fp32
    const float* bias = (const float*)d_in[2];   // (E,)  fp32

    f32x4* out = (f32x4*)d_out;

    const int S     = in_sizes[0];   // B=1
    const int halfS = S / 2;
    const int grid  = S * CHUNKS;    // 2048 blocks: one (i, half-row) tile each

    relpos2d_kernel<<<grid, 256, 0, stream>>>(idxs, W, bias, out, S, halfS);
}

// Round 6
// 96.963 us; speedup vs baseline: 1.1170x; 1.0422x over previous
//
#include <hip/hip_runtime.h>

// RelativePositionalEncoding2D: out[b,i,j,e] = W[e, pos] + bias[e]
//   pos = clip(idxs[b,j] - idxs[b,i], -32, 32) + 32
// Shapes: B=1, S=1024, E=128, N=65. Output fp32 (1,S,S,E) = 512 MiB -> pure
// HBM-write-bound (floor ~80us at ~6.7 TB/s measured fill BW).
//
// R5 -> R6: single-variable A/B — REMOVE the nontemporal hint. The harness's
// fillBufferAligned sustains 83% of peak with PLAIN stores; our nt stores sit
// at 66%. Theory: nt changes write MTYPE (L2 bypass/evict-first) and throttles
// the drain path for full-line streaming writes. Everything else identical
// to R5 (coalesced prologue, 2048 half-row blocks, unroll 4).

#define MAXGAP 32
#define NIDX   65     // 2*MAXGAP+1
#define EDIM   128
#define E4     32     // EDIM/4 float4 per output row
#define PADE   132    // padded row stride in floats (528B, 16B-aligned)
#define CHUNKS 2      // half-rows per i

typedef float f32x4 __attribute__((ext_vector_type(4)));

__global__ __launch_bounds__(256) void relpos2d_kernel(
    const int* __restrict__ idxs,
    const float* __restrict__ W,       // (E, N) row-major
    const float* __restrict__ bias,    // (E,)
    f32x4* __restrict__ out,           // (S*S, E4)
    int S, int halfS)
{
    __shared__ float table[NIDX * PADE];  // 65*132*4 = 34,320 B
    __shared__ int   jidx[512];           // halfS entries

    // table[p][e] = W[e*N + p] + bias[e]; read W coalesced, scatter to LDS.
    for (int t = threadIdx.x; t < NIDX * EDIM; t += 256) {
        float w = W[t];              // coalesced: t = e*NIDX + p
        int e = t / NIDX;            // magic-mul (constant divisor)
        int p = t - e * NIDX;
        table[p * PADE + e] = w + bias[e];
    }

    const int i     = blockIdx.x >> 1;       // CHUNKS == 2
    const int chunk = blockIdx.x & (CHUNKS - 1);
    const int jbase = chunk * halfS;

    // stage this block's idxs[j] slice
    for (int t = threadIdx.x; t < halfS; t += 256)
        jidx[t] = idxs[jbase + t];

    __syncthreads();

    const int lane4 = threadIdx.x & 31;   // float4 slot within the 512B row
    const int jsub  = threadIdx.x >> 5;   // 0..7: j within this step
    const int idx_i = idxs[i];

    f32x4* __restrict__ orow = out + (size_t)i * S * E4 + (size_t)jbase * E4;

    #pragma unroll 4
    for (int jj = 0; jj < halfS; jj += 8) {
        int j = jj + jsub;
        int d = jidx[j] - idx_i;                       // LDS broadcast read
        d = d < -MAXGAP ? -MAXGAP : (d > MAXGAP ? MAXGAP : d);
        int p = d + MAXGAP;

        f32x4 v = reinterpret_cast<const f32x4*>(&table[p * PADE])[lane4];
        orow[(size_t)j * E4 + lane4] = v;              // plain store (A/B vs nt)
    }
}

extern "C" void kernel_launch(void* const* d_in, const int* in_sizes, int n_in,
                              void* d_out, int out_size, void* d_ws, size_t ws_size,
                              hipStream_t stream) {
    const int*   idxs = (const int*)  d_in[0];   // (B*S,) int32, B=1
    const float* W    = (const float*)d_in[1];   // (E, N) fp32
    const float* bias = (const float*)d_in[2];   // (E,)  fp32

    f32x4* out = (f32x4*)d_out;

    const int S     = in_sizes[0];   // B=1
    const int halfS = S / 2;
    const int grid  = S * CHUNKS;    // 2048 blocks: one (i, half-row) tile each

    relpos2d_kernel<<<grid, 256, 0, stream>>>(idxs, W, bias, out, S, halfS);
}